// Round 3
// baseline (367.986 us; speedup 1.0000x reference)
//
#include <hip/hip_runtime.h>
#include <cstdint>
#include <cstddef>

// ---------------------------------------------------------------------------
// GatingNetwork r3: fp16x2 Markidis 3-product MFMA (verified layouts from r2),
// super-chunk LDS staging of x (K=256 per barrier pair -> 8 barrier-free
// chunks), 1024-thread blocks with 32x64 wave tiles (acc=32 VGPR, 4 waves/
// SIMD), stride-260 LDS + b64 reads (conflict-free), epilogue params from L2.
// Scales: A=64x, B=64w, lo-of-B pre-scaled 2^8; h held at scale 2^12.
// ---------------------------------------------------------------------------

typedef _Float16 f16;
typedef _Float16 f16x4 __attribute__((ext_vector_type(4)));
typedef _Float16 f16x8 __attribute__((ext_vector_type(8)));
typedef float f32x4 __attribute__((ext_vector_type(4)));

#define B_ROWS 65536
#define D_DIM 1024
#define H_DIM 512
#define E_DIM 8
#define BM 64
#define BK 32
#define THREADS 1024
#define NSUPER 4
#define KSUP 256                        // K per super-chunk
#define NCH 8                           // chunks per super-chunk
#define LDSS 260                        // x-slab row stride in halves (520 B: 8-aligned, 2-way max)
#define IMG_CH (H_DIM * BK)             // 16384 halves per K-chunk image
#define IMG_TOTAL (32 * IMG_CH)         // 524288 halves = 1 MB per image
#define GACC_OFF ((size_t)2 * IMG_TOTAL * sizeof(f16))  // 2 MB

// ---- prep: split W1 into fp16 hi/lo images in MFMA B-fragment order --------
// img[c][col][kk]: lane reads col*32 + l4*8 within chunk image c.
__global__ void prep_split(const float* __restrict__ W1,
                           f16* __restrict__ wh, f16* __restrict__ wl) {
  int id = blockIdx.x * 256 + threadIdx.x;   // 65536 threads
  int h = id & (H_DIM - 1);
  int kg = id >> 9;                          // 0..127
  int c = kg >> 2;
  int kk0 = (kg & 3) * 8;
  int k0 = kg * 8;
  f16x8 hv, lv;
#pragma unroll
  for (int j = 0; j < 8; ++j) {
    float v = W1[(size_t)(k0 + j) * H_DIM + h] * 64.0f;
    f16 hi = (f16)v;
    hv[j] = hi;
    lv[j] = (f16)((v - (float)hi) * 256.0f);  // residual pre-scaled 2^8 (normal range)
  }
  size_t o = (size_t)c * IMG_CH + (size_t)h * BK + kk0;
  *(f16x8*)&wh[o] = hv;
  *(f16x8*)&wl[o] = lv;
}

__global__ void zero_acc(float* __restrict__ acc) {
  if (threadIdx.x < 16) acc[threadIdx.x] = 0.0f;
}

// ---- main fused kernel -----------------------------------------------------
__global__ __launch_bounds__(THREADS, 4) void fused_main(
    const float* __restrict__ x,
    const f16* __restrict__ wh, const f16* __restrict__ wl,
    const float* __restrict__ b1, const float* __restrict__ lnw,
    const float* __restrict__ lnb, const float* __restrict__ W2,
    const float* __restrict__ b2, float* __restrict__ out,
    float* __restrict__ gacc) {
  // GEMM phase: sXh [0,33280) sXl [33280,66560). Epilogue overlays [0,21056).
  __shared__ __align__(16) char pool[66560];
  f16* sXh = (f16*)pool;
  f16* sXl = (f16*)(pool + 33280);

  const int tid = threadIdx.x;
  const int lane = tid & 63;
  const int wv = tid >> 6;        // 0..15
  const int ng = wv & 7;          // col group: cols ng*64..+63
  const int mg = wv >> 3;         // row group: rows mg*32..+31
  const int l15 = lane & 15;
  const int l4 = lane >> 4;       // 0..3
  const int64_t row0 = (int64_t)blockIdx.x * BM;

  // staging: thread stages row tid>>4, 16 floats at col (tid&15)*16
  const int srow = tid >> 4;
  const int sk0 = (tid & 15) * 16;
  const int swo = srow * LDSS + sk0;

  // B fragment base (fragment-order image): frag n at + n*512
  const size_t boff = (size_t)(ng * 64 + l15) * BK + l4 * 8;

  f32x4 acc[2][4];
#pragma unroll
  for (int m = 0; m < 2; ++m)
#pragma unroll
    for (int n = 0; n < 4; ++n) acc[m][n] = (f32x4){0.f, 0.f, 0.f, 0.f};

  for (int sc = 0; sc < NSUPER; ++sc) {
    // issue x loads for this super BEFORE the barrier (latency hides under
    // the previous super's compute tail)
    float4 v[4];
    {
      const float* xs = x + (row0 + srow) * D_DIM + sc * KSUP + sk0;
#pragma unroll
      for (int j = 0; j < 4; ++j) v[j] = *(const float4*)(xs + 4 * j);
    }
    __syncthreads();   // all waves done reading previous super's slab
    // split & write slab
#pragma unroll
    for (int j = 0; j < 4; ++j) {
      float vv[4] = {v[j].x, v[j].y, v[j].z, v[j].w};
      f16x4 hv, lv;
#pragma unroll
      for (int q = 0; q < 4; ++q) {
        float t = vv[q] * 64.0f;
        f16 hh = (f16)t;
        hv[q] = hh;
        lv[q] = (f16)(t - (float)hh);
      }
      *(f16x4*)&sXh[swo + 4 * j] = hv;
      *(f16x4*)&sXl[swo + 4 * j] = lv;
    }
    __syncthreads();
    // 8 barrier-free K-chunks
#pragma unroll
    for (int cc = 0; cc < NCH; ++cc) {
      const int kg = sc * NCH + cc;
      const f16* whc = wh + (size_t)kg * IMG_CH + boff;
      const f16* wlc = wl + (size_t)kg * IMG_CH + boff;
      f16x8 bh[4], bl[4];
#pragma unroll
      for (int n = 0; n < 4; ++n) {
        bh[n] = *(const f16x8*)(whc + n * 512);
        bl[n] = *(const f16x8*)(wlc + n * 512);
      }
#pragma unroll
      for (int m = 0; m < 2; ++m) {
        const int o = (mg * 32 + m * 16 + l15) * LDSS + cc * BK + l4 * 8;
        f16x4 h0 = *(const f16x4*)&sXh[o];
        f16x4 h1 = *(const f16x4*)&sXh[o + 4];
        f16x4 l0 = *(const f16x4*)&sXl[o];
        f16x4 l1 = *(const f16x4*)&sXl[o + 4];
        f16x8 ah, al, ahs;
#pragma unroll
        for (int q = 0; q < 4; ++q) {
          ah[q] = h0[q]; ah[q + 4] = h1[q];
          al[q] = l0[q]; al[q + 4] = l1[q];
        }
#pragma unroll
        for (int q = 0; q < 8; ++q) ahs[q] = ah[q] * (f16)0.00390625f;  // 2^-8
#pragma unroll
        for (int n = 0; n < 4; ++n) {
          acc[m][n] = __builtin_amdgcn_mfma_f32_16x16x32_f16(ah, bh[n], acc[m][n], 0, 0, 0);
          acc[m][n] = __builtin_amdgcn_mfma_f32_16x16x32_f16(al, bh[n], acc[m][n], 0, 0, 0);
          acc[m][n] = __builtin_amdgcn_mfma_f32_16x16x32_f16(ahs, bl[n], acc[m][n], 0, 0, 0);
        }
      }
    }
  }
  __syncthreads();  // GEMM done; overlay epilogue region

  // ---------------- epilogue (h at scale 2^12 in acc) -----------------------
  float* eStat = (float*)pool;             // [8][64][2]
  float* eLog = (float*)(pool + 4096);     // [8][64][8]
  float* eMu = (float*)(pool + 20480);     // [64]
  float* eRs = (float*)(pool + 20736);     // [64]
  float* eFP = (float*)(pool + 20992);     // [16]

  // per-column params straight from L2 (b1/lnw/lnb/W2 are tiny + hot)
  float bb[4], lw[4], lb[4], w2c[4][8];
#pragma unroll
  for (int n = 0; n < 4; ++n) {
    int col = ng * 64 + n * 16 + l15;
    bb[n] = b1[col] * 4096.0f;
    lw[n] = lnw[col];
    lb[n] = lnb[col];
    *(float4*)&w2c[n][0] = *(const float4*)&W2[col * 8];
    *(float4*)&w2c[n][4] = *(const float4*)&W2[col * 8 + 4];
  }
  if (tid < 16) eFP[tid] = 0.0f;

  // h += b1 (scaled)
#pragma unroll
  for (int m = 0; m < 2; ++m)
#pragma unroll
    for (int n = 0; n < 4; ++n)
#pragma unroll
      for (int r = 0; r < 4; ++r) acc[m][n][r] += bb[n];

  // row stats: partial over this wave's 64 cols (n x l15), deterministic combine
#pragma unroll
  for (int m = 0; m < 2; ++m) {
    float s1[4] = {0, 0, 0, 0};
    float s2[4] = {0, 0, 0, 0};
#pragma unroll
    for (int n = 0; n < 4; ++n)
#pragma unroll
      for (int r = 0; r < 4; ++r) {
        float vv = acc[m][n][r];
        s1[r] += vv;
        s2[r] = fmaf(vv, vv, s2[r]);
      }
#pragma unroll
    for (int d = 1; d < 16; d <<= 1)
#pragma unroll
      for (int r = 0; r < 4; ++r) {
        s1[r] += __shfl_xor(s1[r], d);
        s2[r] += __shfl_xor(s2[r], d);
      }
    if (l15 == 0) {
      int rb = mg * 32 + m * 16 + l4 * 4;
#pragma unroll
      for (int r = 0; r < 4; ++r) {
        eStat[(ng * 64 + rb + r) * 2 + 0] = s1[r];
        eStat[(ng * 64 + rb + r) * 2 + 1] = s2[r];
      }
    }
  }
  __syncthreads();
  if (tid < BM) {
    float s1 = 0.0f, s2 = 0.0f;
#pragma unroll
    for (int w = 0; w < 8; ++w) {
      s1 += eStat[(w * 64 + tid) * 2 + 0];
      s2 += eStat[(w * 64 + tid) * 2 + 1];
    }
    float mu = s1 * (1.0f / 512.0f);
    float var = s2 * (1.0f / 512.0f) - mu * mu;
    eMu[tid] = mu;
    eRs[tid] = 1.0f / sqrtf(var + (1e-5f * 4096.0f * 4096.0f));
  }
  __syncthreads();

  // LN + exact-erf GELU + per-wave partial logits
#pragma unroll
  for (int m = 0; m < 2; ++m) {
    float lg[4][8];
#pragma unroll
    for (int r = 0; r < 4; ++r)
#pragma unroll
      for (int e = 0; e < 8; ++e) lg[r][e] = 0.0f;
    int rb = mg * 32 + m * 16 + l4 * 4;
    float mu_r[4], rs_r[4];
#pragma unroll
    for (int r = 0; r < 4; ++r) {
      mu_r[r] = eMu[rb + r];
      rs_r[r] = eRs[rb + r];
    }
#pragma unroll
    for (int n = 0; n < 4; ++n) {
#pragma unroll
      for (int r = 0; r < 4; ++r) {
        float hn = (acc[m][n][r] - mu_r[r]) * rs_r[r];
        float y = fmaf(hn, lw[n], lb[n]);
        float g = 0.5f * y * (1.0f + erff(y * 0.70710678118654752440f));
#pragma unroll
        for (int e = 0; e < 8; ++e) lg[r][e] = fmaf(g, w2c[n][e], lg[r][e]);
      }
    }
#pragma unroll
    for (int d = 1; d < 16; d <<= 1)
#pragma unroll
      for (int r = 0; r < 4; ++r)
#pragma unroll
        for (int e = 0; e < 8; ++e) lg[r][e] += __shfl_xor(lg[r][e], d);
    if (l15 == 0) {
#pragma unroll
      for (int r = 0; r < 4; ++r)
#pragma unroll
        for (int e = 0; e < 8; ++e) eLog[(ng * 64 + rb + r) * 8 + e] = lg[r][e];
    }
  }
  __syncthreads();

  // top-2 + sparse softmax + write + load-balance partials
  if (tid < BM) {
    float v[8];
#pragma unroll
    for (int e = 0; e < 8; ++e) {
      float s = b2[e];
#pragma unroll
      for (int w = 0; w < 8; ++w) s += eLog[(w * 64 + tid) * 8 + e];
      v[e] = s;
    }
    float m1 = v[0];
    int i1 = 0;
#pragma unroll
    for (int e = 1; e < 8; ++e)
      if (v[e] > m1) { m1 = v[e]; i1 = e; }   // strict >: lowest index wins ties
    float m2 = -3.0e38f;
    int i2 = -1;
#pragma unroll
    for (int e = 0; e < 8; ++e)
      if (e != i1 && v[e] > m2) { m2 = v[e]; i2 = e; }
    float dd = expf(m2 - m1);
    float inv = 1.0f / (1.0f + dd);
    float wA = inv, wB = dd * inv;
    float o[8];
#pragma unroll
    for (int e = 0; e < 8; ++e)
      o[e] = (e == i1) ? wA : ((e == i2) ? wB : 0.0f);
    float4* op = (float4*)&out[(row0 + tid) * 8];
    op[0] = (float4){o[0], o[1], o[2], o[3]};
    op[1] = (float4){o[4], o[5], o[6], o[7]};
    atomicAdd(&eFP[i1], 1.0f);
    atomicAdd(&eFP[i2], 1.0f);
    atomicAdd(&eFP[8 + i1], wA);
    atomicAdd(&eFP[8 + i2], wB);
  }
  __syncthreads();
  if (tid < 16) atomicAdd(&gacc[tid], eFP[tid]);
}

// ---- finalize load-balance loss --------------------------------------------
__global__ void lb_final(const float* __restrict__ gacc, float* __restrict__ out) {
  if (threadIdx.x == 0) {
    const float invB = 1.0f / 65536.0f;
    float s = 0.0f;
#pragma unroll
    for (int e = 0; e < 8; ++e) s += (gacc[e] * invB) * (gacc[8 + e] * invB);
    out[(size_t)B_ROWS * E_DIM] = 0.01f * 8.0f * s;
  }
}

// ---- launch ----------------------------------------------------------------
extern "C" void kernel_launch(void* const* d_in, const int* in_sizes, int n_in,
                              void* d_out, int out_size, void* d_ws, size_t ws_size,
                              hipStream_t stream) {
  (void)in_sizes; (void)n_in; (void)out_size; (void)ws_size;
  const float* x = (const float*)d_in[0];
  const float* W1 = (const float*)d_in[1];
  const float* b1 = (const float*)d_in[2];
  const float* lnw = (const float*)d_in[3];
  const float* lnb = (const float*)d_in[4];
  const float* W2 = (const float*)d_in[5];
  const float* b2 = (const float*)d_in[6];
  float* out = (float*)d_out;
  f16* wh = (f16*)d_ws;
  f16* wl = wh + IMG_TOTAL;
  float* gacc = (float*)((char*)d_ws + GACC_OFF);  // ws needs ~2.1 MB

  zero_acc<<<1, 64, 0, stream>>>(gacc);
  prep_split<<<(D_DIM * H_DIM / 8) / 256, 256, 0, stream>>>(W1, wh, wl);
  fused_main<<<B_ROWS / BM, THREADS, 0, stream>>>(x, wh, wl, b1, lnw, lnb, W2, b2,
                                                  out, gacc);
  lb_final<<<1, 64, 0, stream>>>(gacc, out);
}

// Round 4
// 326.028 us; speedup vs baseline: 1.1287x; 1.1287x over previous
//
#include <hip/hip_runtime.h>
#include <cstdint>
#include <cstddef>

// ---------------------------------------------------------------------------
// GatingNetwork r4: R2's verified geometry (512 thr, 8 waves, wave=64x64,
// acc[4][4], fragment-order B images in L2) + software-pipelined B loads
// (2 register sets, half-chunk granularity, issue-to-use distance ~1 half)
// + barrier every 2 chunks (super K=64) + x prefetched one super ahead.
// Numerics (verified r1-r3): A=64x hi/lo fp16, B=64w hi/lo fp16 with lo
// pre-scaled 2^8; 3-product Markidis MFMA; h held at scale 2^12.
// ---------------------------------------------------------------------------

typedef _Float16 f16;
typedef _Float16 f16x8 __attribute__((ext_vector_type(8)));
typedef float f32x4 __attribute__((ext_vector_type(4)));

#define B_ROWS 65536
#define D_DIM 1024
#define H_DIM 512
#define E_DIM 8
#define BM 64
#define BK 32
#define THREADS 512
#define NSUPER 16                        // K = 16 supers x 64
#define LDPX 72                          // slab row stride in halves (144 B, mult of 16 B)
#define SLABH 4608                       // halves per image slab (64 rows x 72)
#define BUFH 9216                        // halves per buffer (hi + lo)
#define IMG_CH (H_DIM * BK)              // 16384 halves per K-chunk B image
#define IMG_TOTAL (32 * IMG_CH)          // 524288 halves = 1 MB per image
#define GACC_OFF ((size_t)2 * IMG_TOTAL * sizeof(f16))  // 2 MB

// ---- prep: split W1 into fp16 hi/lo images in MFMA B-fragment order --------
// img[c][col][kk]: lane reads (col)*32 + l4*8 within chunk image c. (r2-verified)
__global__ void prep_split(const float* __restrict__ W1,
                           f16* __restrict__ wh, f16* __restrict__ wl) {
  int id = blockIdx.x * 256 + threadIdx.x;   // 65536 threads
  int h = id & (H_DIM - 1);
  int kg = id >> 9;                          // 0..127
  int c = kg >> 2;
  int kk0 = (kg & 3) * 8;
  int k0 = kg * 8;
  f16x8 hv, lv;
#pragma unroll
  for (int j = 0; j < 8; ++j) {
    float v = W1[(size_t)(k0 + j) * H_DIM + h] * 64.0f;
    f16 hi = (f16)v;
    hv[j] = hi;
    lv[j] = (f16)((v - (float)hi) * 256.0f);  // residual pre-scaled 2^8 (normal range)
  }
  size_t o = (size_t)c * IMG_CH + (size_t)h * BK + kk0;
  *(f16x8*)&wh[o] = hv;
  *(f16x8*)&wl[o] = lv;
}

__global__ void zero_acc(float* __restrict__ acc) {
  if (threadIdx.x < 16) acc[threadIdx.x] = 0.0f;
}

// ---- main fused kernel -----------------------------------------------------
__global__ __launch_bounds__(THREADS, 3) void fused_main(
    const float* __restrict__ x,
    const f16* __restrict__ wh, const f16* __restrict__ wl,
    const float* __restrict__ b1, const float* __restrict__ lnw,
    const float* __restrict__ lnb, const float* __restrict__ W2,
    const float* __restrict__ b2, float* __restrict__ out,
    float* __restrict__ gacc) {
  // GEMM: 2 x-slab buffers (hi+lo each), 36864 B. Epilogue overlays [0,21056).
  __shared__ __align__(16) char pool[36864];
  f16* sx = (f16*)pool;

  const int tid = threadIdx.x;
  const int lane = tid & 63;
  const int wv = tid >> 6;        // 0..7 : wave owns cols wv*64..+63, all 64 rows
  const int l15 = lane & 15;
  const int l4 = lane >> 4;       // 0..3
  const int64_t row0 = (int64_t)blockIdx.x * BM;

  // staging: thread stages row tid>>3, 8 floats at k-group (tid&7)*8
  const int srow = tid >> 3;
  const int kg = tid & 7;
  const int swo = srow * LDPX + kg * 8;
  const float* xbase = x + (row0 + srow) * D_DIM + kg * 8;

  // B lane offset within a chunk image (fragment order, r2-verified)
  const int blane = (wv * 64 + l15) * BK + l4 * 8;

  f32x4 acc[4][4];
#pragma unroll
  for (int m = 0; m < 4; ++m)
#pragma unroll
    for (int n = 0; n < 4; ++n) acc[m][n] = (f32x4){0.f, 0.f, 0.f, 0.f};

  // two B register sets: [set][0..1]=bh frags, [2..3]=bl frags
  f16x8 setB[2][4];

#define ISSUE(si, H)                                                          \
  do {                                                                        \
    const int Hc = (H) & 63;                                                  \
    const f16* p = wh + (size_t)(Hc >> 1) * IMG_CH + ((Hc & 1) ? 1024 : 0) +  \
                   blane;                                                     \
    setB[si][0] = *(const f16x8*)(p);                                         \
    setB[si][1] = *(const f16x8*)(p + 512);                                   \
    setB[si][2] = *(const f16x8*)(p + IMG_TOTAL);                             \
    setB[si][3] = *(const f16x8*)(p + IMG_TOTAL + 512);                       \
  } while (0)

#define HALF(si, ch, nh, bufv)                                                \
  do {                                                                        \
    _Pragma("unroll") for (int m = 0; m < 4; ++m) {                           \
      const int ao = (bufv)*BUFH + (m * 16 + l15) * LDPX + (ch)*32 + l4 * 8;  \
      f16x8 ah = *(const f16x8*)&sx[ao];                                      \
      f16x8 al = *(const f16x8*)&sx[ao + SLABH];                              \
      f16x8 ahs;                                                              \
      _Pragma("unroll") for (int q = 0; q < 8; ++q) ahs[q] =                  \
          ah[q] * (f16)0.00390625f;                                           \
      acc[m][(nh)*2 + 0] = __builtin_amdgcn_mfma_f32_16x16x32_f16(            \
          ah, setB[si][0], acc[m][(nh)*2 + 0], 0, 0, 0);                      \
      acc[m][(nh)*2 + 0] = __builtin_amdgcn_mfma_f32_16x16x32_f16(            \
          al, setB[si][0], acc[m][(nh)*2 + 0], 0, 0, 0);                      \
      acc[m][(nh)*2 + 0] = __builtin_amdgcn_mfma_f32_16x16x32_f16(            \
          ahs, setB[si][2], acc[m][(nh)*2 + 0], 0, 0, 0);                     \
      acc[m][(nh)*2 + 1] = __builtin_amdgcn_mfma_f32_16x16x32_f16(            \
          ah, setB[si][1], acc[m][(nh)*2 + 1], 0, 0, 0);                      \
      acc[m][(nh)*2 + 1] = __builtin_amdgcn_mfma_f32_16x16x32_f16(            \
          al, setB[si][1], acc[m][(nh)*2 + 1], 0, 0, 0);                      \
      acc[m][(nh)*2 + 1] = __builtin_amdgcn_mfma_f32_16x16x32_f16(            \
          ahs, setB[si][3], acc[m][(nh)*2 + 1], 0, 0, 0);                     \
    }                                                                         \
  } while (0)

#define WRITE_SLAB(bufv)                                                      \
  do {                                                                        \
    float vv[8] = {xv0.x, xv0.y, xv0.z, xv0.w, xv1.x, xv1.y, xv1.z, xv1.w};   \
    f16x8 hv, lv;                                                             \
    _Pragma("unroll") for (int j = 0; j < 8; ++j) {                           \
      float t = vv[j] * 64.0f;                                                \
      f16 hh = (f16)t;                                                        \
      hv[j] = hh;                                                             \
      lv[j] = (f16)(t - (float)hh);                                           \
    }                                                                         \
    *(f16x8*)&sx[(bufv)*BUFH + swo] = hv;                                     \
    *(f16x8*)&sx[(bufv)*BUFH + SLABH + swo] = lv;                             \
  } while (0)

  // ---- prologue: slab 0, B sets for halves 0,1, x prefetch for super 1 ----
  float4 xv0 = *(const float4*)(xbase);
  float4 xv1 = *(const float4*)(xbase + 4);
  WRITE_SLAB(0);
  ISSUE(0, 0);
  ISSUE(1, 1);
  xv0 = *(const float4*)(xbase + 64);
  xv1 = *(const float4*)(xbase + 68);
  __syncthreads();

  for (int s = 0; s < NSUPER; ++s) {
    const int buf = s & 1;
    const int H0 = s * 4;
    HALF(0, 0, 0, buf);          // consume set0 (half H0)
    ISSUE(0, H0 + 2);            // refill for half H0+2
    HALF(1, 0, 1, buf);          // consume set1 (half H0+1)
    ISSUE(1, H0 + 3);
    HALF(0, 1, 0, buf);          // set0 = half H0+2
    ISSUE(0, H0 + 4);            // next super's half 0 (crosses barrier)
    HALF(1, 1, 1, buf);          // set1 = half H0+3
    ISSUE(1, H0 + 5);
    if (s + 1 < NSUPER) WRITE_SLAB(buf ^ 1);      // slab for super s+1 (other buffer)
    if (s + 2 < NSUPER) {                          // x for super s+2 (full-super cover)
      xv0 = *(const float4*)(xbase + (s + 2) * 64);
      xv1 = *(const float4*)(xbase + (s + 2) * 64 + 4);
    }
    __syncthreads();
  }
#undef ISSUE
#undef HALF
#undef WRITE_SLAB

  // ---------------- epilogue (h at scale 2^12 in acc; r2-verified) ----------
  float* eStat = (float*)pool;             // [8][64][2] = 4096 B
  float* eLog = (float*)(pool + 4096);     // [8][64][8] = 16384 B
  float* eMu = (float*)(pool + 20480);     // [64]
  float* eRs = (float*)(pool + 20736);     // [64]
  float* eFP = (float*)(pool + 20992);     // [16]

  // per-column params straight from L2 (tiny + hot; r3-verified pattern)
  float bb[4], lw[4], lb[4], w2c[4][8];
#pragma unroll
  for (int n = 0; n < 4; ++n) {
    int col = wv * 64 + n * 16 + l15;
    bb[n] = b1[col] * 4096.0f;
    lw[n] = lnw[col];
    lb[n] = lnb[col];
    *(float4*)&w2c[n][0] = *(const float4*)&W2[col * 8];
    *(float4*)&w2c[n][4] = *(const float4*)&W2[col * 8 + 4];
  }
  if (tid < 16) eFP[tid] = 0.0f;

  // h += b1 (scaled)
#pragma unroll
  for (int n = 0; n < 4; ++n)
#pragma unroll
    for (int m = 0; m < 4; ++m)
#pragma unroll
      for (int r = 0; r < 4; ++r) acc[m][n][r] += bb[n];

  // row stats: partial over this wave's 64 cols, deterministic combine
#pragma unroll
  for (int m = 0; m < 4; ++m) {
    float s1[4] = {0, 0, 0, 0};
    float s2[4] = {0, 0, 0, 0};
#pragma unroll
    for (int n = 0; n < 4; ++n)
#pragma unroll
      for (int r = 0; r < 4; ++r) {
        float vv = acc[m][n][r];
        s1[r] += vv;
        s2[r] = fmaf(vv, vv, s2[r]);
      }
#pragma unroll
    for (int d = 1; d < 16; d <<= 1)
#pragma unroll
      for (int r = 0; r < 4; ++r) {
        s1[r] += __shfl_xor(s1[r], d);
        s2[r] += __shfl_xor(s2[r], d);
      }
    if (l15 == 0) {
      int rb = m * 16 + l4 * 4;
#pragma unroll
      for (int r = 0; r < 4; ++r) {
        eStat[(wv * 64 + rb + r) * 2 + 0] = s1[r];
        eStat[(wv * 64 + rb + r) * 2 + 1] = s2[r];
      }
    }
  }
  __syncthreads();
  if (tid < BM) {
    float s1 = 0.0f, s2 = 0.0f;
#pragma unroll
    for (int w = 0; w < 8; ++w) {
      s1 += eStat[(w * 64 + tid) * 2 + 0];
      s2 += eStat[(w * 64 + tid) * 2 + 1];
    }
    float mu = s1 * (1.0f / 512.0f);
    float var = s2 * (1.0f / 512.0f) - mu * mu;
    eMu[tid] = mu;
    eRs[tid] = 1.0f / sqrtf(var + (1e-5f * 4096.0f * 4096.0f));
  }
  __syncthreads();

  // LN + exact-erf GELU + per-wave partial logits
#pragma unroll
  for (int m = 0; m < 4; ++m) {
    float lg[4][8];
#pragma unroll
    for (int r = 0; r < 4; ++r)
#pragma unroll
      for (int e = 0; e < 8; ++e) lg[r][e] = 0.0f;
    int rb = m * 16 + l4 * 4;
    float mu_r[4], rs_r[4];
#pragma unroll
    for (int r = 0; r < 4; ++r) {
      mu_r[r] = eMu[rb + r];
      rs_r[r] = eRs[rb + r];
    }
#pragma unroll
    for (int n = 0; n < 4; ++n) {
#pragma unroll
      for (int r = 0; r < 4; ++r) {
        float hn = (acc[m][n][r] - mu_r[r]) * rs_r[r];
        float y = fmaf(hn, lw[n], lb[n]);
        float g = 0.5f * y * (1.0f + erff(y * 0.70710678118654752440f));
#pragma unroll
        for (int e = 0; e < 8; ++e) lg[r][e] = fmaf(g, w2c[n][e], lg[r][e]);
      }
    }
#pragma unroll
    for (int d = 1; d < 16; d <<= 1)
#pragma unroll
      for (int r = 0; r < 4; ++r)
#pragma unroll
        for (int e = 0; e < 8; ++e) lg[r][e] += __shfl_xor(lg[r][e], d);
    if (l15 == 0) {
#pragma unroll
      for (int r = 0; r < 4; ++r)
#pragma unroll
        for (int e = 0; e < 8; ++e) eLog[(wv * 64 + rb + r) * 8 + e] = lg[r][e];
    }
  }
  __syncthreads();

  // top-2 + sparse softmax + write + load-balance partials
  if (tid < BM) {
    float v[8];
#pragma unroll
    for (int e = 0; e < 8; ++e) {
      float s = b2[e];
#pragma unroll
      for (int w = 0; w < 8; ++w) s += eLog[(w * 64 + tid) * 8 + e];
      v[e] = s;
    }
    float m1 = v[0];
    int i1 = 0;
#pragma unroll
    for (int e = 1; e < 8; ++e)
      if (v[e] > m1) { m1 = v[e]; i1 = e; }   // strict >: lowest index wins ties
    float m2 = -3.0e38f;
    int i2 = -1;
#pragma unroll
    for (int e = 0; e < 8; ++e)
      if (e != i1 && v[e] > m2) { m2 = v[e]; i2 = e; }
    float dd = expf(m2 - m1);
    float inv = 1.0f / (1.0f + dd);
    float wA = inv, wB = dd * inv;
    float o[8];
#pragma unroll
    for (int e = 0; e < 8; ++e)
      o[e] = (e == i1) ? wA : ((e == i2) ? wB : 0.0f);
    float4* op = (float4*)&out[(row0 + tid) * 8];
    op[0] = (float4){o[0], o[1], o[2], o[3]};
    op[1] = (float4){o[4], o[5], o[6], o[7]};
    atomicAdd(&eFP[i1], 1.0f);
    atomicAdd(&eFP[i2], 1.0f);
    atomicAdd(&eFP[8 + i1], wA);
    atomicAdd(&eFP[8 + i2], wB);
  }
  __syncthreads();
  if (tid < 16) atomicAdd(&gacc[tid], eFP[tid]);
}

// ---- finalize load-balance loss --------------------------------------------
__global__ void lb_final(const float* __restrict__ gacc, float* __restrict__ out) {
  if (threadIdx.x == 0) {
    const float invB = 1.0f / 65536.0f;
    float s = 0.0f;
#pragma unroll
    for (int e = 0; e < 8; ++e) s += (gacc[e] * invB) * (gacc[8 + e] * invB);
    out[(size_t)B_ROWS * E_DIM] = 0.01f * 8.0f * s;
  }
}

// ---- launch ----------------------------------------------------------------
extern "C" void kernel_launch(void* const* d_in, const int* in_sizes, int n_in,
                              void* d_out, int out_size, void* d_ws, size_t ws_size,
                              hipStream_t stream) {
  (void)in_sizes; (void)n_in; (void)out_size; (void)ws_size;
  const float* x = (const float*)d_in[0];
  const float* W1 = (const float*)d_in[1];
  const float* b1 = (const float*)d_in[2];
  const float* lnw = (const float*)d_in[3];
  const float* lnb = (const float*)d_in[4];
  const float* W2 = (const float*)d_in[5];
  const float* b2 = (const float*)d_in[6];
  float* out = (float*)d_out;
  f16* wh = (f16*)d_ws;
  f16* wl = wh + IMG_TOTAL;
  float* gacc = (float*)((char*)d_ws + GACC_OFF);  // ws needs ~2.1 MB

  zero_acc<<<1, 64, 0, stream>>>(gacc);
  prep_split<<<(D_DIM * H_DIM / 8) / 256, 256, 0, stream>>>(W1, wh, wl);
  fused_main<<<B_ROWS / BM, THREADS, 0, stream>>>(x, wh, wl, b1, lnw, lnb, W2, b2,
                                                  out, gacc);
  lb_final<<<1, 64, 0, stream>>>(gacc, out);
}

// Round 5
// 275.674 us; speedup vs baseline: 1.3349x; 1.1827x over previous
//
#include <hip/hip_runtime.h>
#include <cstdint>
#include <cstddef>

// ---------------------------------------------------------------------------
// GatingNetwork r5: R2/R4-verified layouts + the two fixes the R4 counters
// demanded: (1) raw s_barrier with lgkmcnt-only drain (B loads stay in flight
// across super boundaries -> T4 effect), (2) full-chunk B double-set in regs
// (issue-to-use = 48 MFMA ~ 233cyc > L2 latency), designed for 2 waves/SIMD
// (ILP regime, m201-style) instead of fighting the 128-reg cliff.
// + T5 setprio around MFMA clusters.
// Numerics (r1-r4 verified): A=64x hi/lo fp16, B=64w hi/lo fp16 (lo x2^8);
// 3-product Markidis MFMA 16x16x32; h at scale 2^12; fused LN/GELU/top2.
// ---------------------------------------------------------------------------

typedef _Float16 f16;
typedef _Float16 f16x8 __attribute__((ext_vector_type(8)));
typedef float f32x4 __attribute__((ext_vector_type(4)));

#define B_ROWS 65536
#define D_DIM 1024
#define H_DIM 512
#define E_DIM 8
#define BM 64
#define BK 32
#define THREADS 512
#define NSUPER 16                        // 16 supers x K64 (2 chunks each)
#define LDPX 72                          // slab row stride in halves (144 B)
#define SLABH 4608                       // 64 rows x 72 halves (one image)
#define BUFH 9216                        // hi + lo per buffer
#define IMG_CH (H_DIM * BK)              // 16384 halves per K-chunk B image
#define IMG_TOTAL (32 * IMG_CH)          // 1 MB per image
#define GACC_OFF ((size_t)2 * IMG_TOTAL * sizeof(f16))  // 2 MB

// ---- prep: split W1 into fp16 hi/lo images in MFMA B-fragment order --------
__global__ void prep_split(const float* __restrict__ W1,
                           f16* __restrict__ wh, f16* __restrict__ wl) {
  int id = blockIdx.x * 256 + threadIdx.x;   // 65536 threads
  int h = id & (H_DIM - 1);
  int kg = id >> 9;                          // 0..127
  int c = kg >> 2;
  int kk0 = (kg & 3) * 8;
  int k0 = kg * 8;
  f16x8 hv, lv;
#pragma unroll
  for (int j = 0; j < 8; ++j) {
    float v = W1[(size_t)(k0 + j) * H_DIM + h] * 64.0f;
    f16 hi = (f16)v;
    hv[j] = hi;
    lv[j] = (f16)((v - (float)hi) * 256.0f);  // residual pre-scaled 2^8
  }
  size_t o = (size_t)c * IMG_CH + (size_t)h * BK + kk0;
  *(f16x8*)&wh[o] = hv;
  *(f16x8*)&wl[o] = lv;
}

__global__ void zero_acc(float* __restrict__ acc) {
  if (threadIdx.x < 16) acc[threadIdx.x] = 0.0f;
}

// ---- main fused kernel -----------------------------------------------------
__global__ __launch_bounds__(THREADS) void fused_main(
    const float* __restrict__ x,
    const f16* __restrict__ wh, const f16* __restrict__ wl,
    const float* __restrict__ b1, const float* __restrict__ lnw,
    const float* __restrict__ lnb, const float* __restrict__ W2,
    const float* __restrict__ b2, float* __restrict__ out,
    float* __restrict__ gacc) {
  // 2 x-slab buffers (hi+lo each) = 36864 B. Epilogue overlays [0,21056).
  __shared__ __align__(16) char pool[36864];
  f16* sx = (f16*)pool;

  const int tid = threadIdx.x;
  const int lane = tid & 63;
  const int wv = tid >> 6;        // 0..7 : wave owns cols wv*64..+63, all 64 rows
  const int l15 = lane & 15;
  const int l4 = lane >> 4;       // 0..3
  const int64_t row0 = (int64_t)blockIdx.x * BM;

  // staging: thread stages row tid>>3, 8 floats at k-group (tid&7)*8
  const int srow = tid >> 3;
  const int kg = tid & 7;
  const int swo = srow * LDPX + kg * 8;
  const float* xbase = x + (row0 + srow) * D_DIM + kg * 8;

  // B lane offset within a chunk image (fragment order, r2-verified)
  const int blane = (wv * 64 + l15) * BK + l4 * 8;

  f32x4 acc[4][4];
#pragma unroll
  for (int m = 0; m < 4; ++m)
#pragma unroll
    for (int n = 0; n < 4; ++n) acc[m][n] = (f32x4){0.f, 0.f, 0.f, 0.f};

  // two full-chunk B register sets: [set][0..3]=hi frags, [4..7]=lo frags
  f16x8 setB[2][8];

#define ISSUE(si, C)                                                          \
  do {                                                                        \
    const f16* p = wh + (size_t)((C) & 31) * IMG_CH + blane;                  \
    setB[si][0] = *(const f16x8*)(p);                                         \
    setB[si][1] = *(const f16x8*)(p + 512);                                   \
    setB[si][2] = *(const f16x8*)(p + 1024);                                  \
    setB[si][3] = *(const f16x8*)(p + 1536);                                  \
    setB[si][4] = *(const f16x8*)(p + IMG_TOTAL);                             \
    setB[si][5] = *(const f16x8*)(p + IMG_TOTAL + 512);                       \
    setB[si][6] = *(const f16x8*)(p + IMG_TOTAL + 1024);                      \
    setB[si][7] = *(const f16x8*)(p + IMG_TOTAL + 1536);                      \
  } while (0)

#define CHUNK(si, par, bufv)                                                  \
  do {                                                                        \
    __builtin_amdgcn_s_setprio(1);                                            \
    _Pragma("unroll") for (int m = 0; m < 4; ++m) {                           \
      const int ao = (bufv)*BUFH + (m * 16 + l15) * LDPX + (par)*32 + l4 * 8; \
      f16x8 ah = *(const f16x8*)&sx[ao];                                      \
      f16x8 al = *(const f16x8*)&sx[ao + SLABH];                              \
      f16x8 ahs;                                                              \
      _Pragma("unroll") for (int q = 0; q < 8; ++q) ahs[q] =                  \
          ah[q] * (f16)0.00390625f;                                           \
      _Pragma("unroll") for (int n = 0; n < 4; ++n) {                         \
        acc[m][n] = __builtin_amdgcn_mfma_f32_16x16x32_f16(                   \
            ah, setB[si][n], acc[m][n], 0, 0, 0);                             \
        acc[m][n] = __builtin_amdgcn_mfma_f32_16x16x32_f16(                   \
            al, setB[si][n], acc[m][n], 0, 0, 0);                             \
        acc[m][n] = __builtin_amdgcn_mfma_f32_16x16x32_f16(                   \
            ahs, setB[si][4 + n], acc[m][n], 0, 0, 0);                        \
      }                                                                       \
    }                                                                         \
    __builtin_amdgcn_s_setprio(0);                                            \
  } while (0)

#define WRITE_SLAB(bufv)                                                      \
  do {                                                                        \
    float vv[8] = {xv0.x, xv0.y, xv0.z, xv0.w, xv1.x, xv1.y, xv1.z, xv1.w};   \
    f16x8 hv, lv;                                                             \
    _Pragma("unroll") for (int j = 0; j < 8; ++j) {                           \
      float t = vv[j] * 64.0f;                                                \
      f16 hh = (f16)t;                                                        \
      hv[j] = hh;                                                             \
      lv[j] = (f16)(t - (float)hh);                                           \
    }                                                                         \
    *(f16x8*)&sx[(bufv)*BUFH + swo] = hv;                                     \
    *(f16x8*)&sx[(bufv)*BUFH + SLABH + swo] = lv;                             \
  } while (0)

  // raw barrier: drain only LDS writes, keep global loads in flight (T4)
#define SLAB_BARRIER()                                                        \
  do {                                                                        \
    asm volatile("s_waitcnt lgkmcnt(0)" ::: "memory");                        \
    __builtin_amdgcn_s_barrier();                                             \
    __builtin_amdgcn_sched_barrier(0);                                        \
  } while (0)

  // ---- prologue: slab for super 0, B sets for chunks 0/1, x for super 1 ----
  float4 xv0 = *(const float4*)(xbase);
  float4 xv1 = *(const float4*)(xbase + 4);
  WRITE_SLAB(0);
  ISSUE(0, 0);
  ISSUE(1, 1);
  xv0 = *(const float4*)(xbase + 64);
  xv1 = *(const float4*)(xbase + 68);
  SLAB_BARRIER();

  for (int s = 0; s < NSUPER; ++s) {
    const int buf = s & 1;
    CHUNK(0, 0, buf);            // chunk 2s   (set0, issued 1 chunk+ ago)
    ISSUE(0, 2 * s + 2);         // refill set0 for chunk 2s+2
    CHUNK(1, 1, buf);            // chunk 2s+1
    ISSUE(1, 2 * s + 3);         // refill set1 for chunk 2s+3
    if (s < NSUPER - 1) WRITE_SLAB(buf ^ 1);   // slab for super s+1
    if (s < NSUPER - 2) {                      // x for super s+2
      xv0 = *(const float4*)(xbase + (s + 2) * 64);
      xv1 = *(const float4*)(xbase + (s + 2) * 64 + 4);
    }
    SLAB_BARRIER();
  }
#undef ISSUE
#undef CHUNK
#undef WRITE_SLAB
#undef SLAB_BARRIER

  // ---------------- epilogue (h at scale 2^12 in acc; r2-verified) ----------
  float* eStat = (float*)pool;             // [8][64][2] = 4096 B
  float* eLog = (float*)(pool + 4096);     // [8][64][8] = 16384 B
  float* eMu = (float*)(pool + 20480);     // [64]
  float* eRs = (float*)(pool + 20736);     // [64]
  float* eFP = (float*)(pool + 20992);     // [16]

  // per-column params straight from L2 (tiny + hot)
  float bb[4], lw[4], lb[4], w2c[4][8];
#pragma unroll
  for (int n = 0; n < 4; ++n) {
    int col = wv * 64 + n * 16 + l15;
    bb[n] = b1[col] * 4096.0f;
    lw[n] = lnw[col];
    lb[n] = lnb[col];
    *(float4*)&w2c[n][0] = *(const float4*)&W2[col * 8];
    *(float4*)&w2c[n][4] = *(const float4*)&W2[col * 8 + 4];
  }
  if (tid < 16) eFP[tid] = 0.0f;

  // h += b1 (scaled)
#pragma unroll
  for (int n = 0; n < 4; ++n)
#pragma unroll
    for (int m = 0; m < 4; ++m)
#pragma unroll
      for (int r = 0; r < 4; ++r) acc[m][n][r] += bb[n];

  // row stats: partial over this wave's 64 cols, deterministic combine
#pragma unroll
  for (int m = 0; m < 4; ++m) {
    float s1[4] = {0, 0, 0, 0};
    float s2[4] = {0, 0, 0, 0};
#pragma unroll
    for (int n = 0; n < 4; ++n)
#pragma unroll
      for (int r = 0; r < 4; ++r) {
        float vv = acc[m][n][r];
        s1[r] += vv;
        s2[r] = fmaf(vv, vv, s2[r]);
      }
#pragma unroll
    for (int d = 1; d < 16; d <<= 1)
#pragma unroll
      for (int r = 0; r < 4; ++r) {
        s1[r] += __shfl_xor(s1[r], d);
        s2[r] += __shfl_xor(s2[r], d);
      }
    if (l15 == 0) {
      int rb = m * 16 + l4 * 4;
#pragma unroll
      for (int r = 0; r < 4; ++r) {
        eStat[(wv * 64 + rb + r) * 2 + 0] = s1[r];
        eStat[(wv * 64 + rb + r) * 2 + 1] = s2[r];
      }
    }
  }
  __syncthreads();
  if (tid < BM) {
    float s1 = 0.0f, s2 = 0.0f;
#pragma unroll
    for (int w = 0; w < 8; ++w) {
      s1 += eStat[(w * 64 + tid) * 2 + 0];
      s2 += eStat[(w * 64 + tid) * 2 + 1];
    }
    float mu = s1 * (1.0f / 512.0f);
    float var = s2 * (1.0f / 512.0f) - mu * mu;
    eMu[tid] = mu;
    eRs[tid] = 1.0f / sqrtf(var + (1e-5f * 4096.0f * 4096.0f));
  }
  __syncthreads();

  // LN + exact-erf GELU + per-wave partial logits
#pragma unroll
  for (int m = 0; m < 4; ++m) {
    float lg[4][8];
#pragma unroll
    for (int r = 0; r < 4; ++r)
#pragma unroll
      for (int e = 0; e < 8; ++e) lg[r][e] = 0.0f;
    int rb = m * 16 + l4 * 4;
    float mu_r[4], rs_r[4];
#pragma unroll
    for (int r = 0; r < 4; ++r) {
      mu_r[r] = eMu[rb + r];
      rs_r[r] = eRs[rb + r];
    }
#pragma unroll
    for (int n = 0; n < 4; ++n) {
#pragma unroll
      for (int r = 0; r < 4; ++r) {
        float hn = (acc[m][n][r] - mu_r[r]) * rs_r[r];
        float y = fmaf(hn, lw[n], lb[n]);
        float g = 0.5f * y * (1.0f + erff(y * 0.70710678118654752440f));
#pragma unroll
        for (int e = 0; e < 8; ++e) lg[r][e] = fmaf(g, w2c[n][e], lg[r][e]);
      }
    }
#pragma unroll
    for (int d = 1; d < 16; d <<= 1)
#pragma unroll
      for (int r = 0; r < 4; ++r)
#pragma unroll
        for (int e = 0; e < 8; ++e) lg[r][e] += __shfl_xor(lg[r][e], d);
    if (l15 == 0) {
#pragma unroll
      for (int r = 0; r < 4; ++r)
#pragma unroll
        for (int e = 0; e < 8; ++e) eLog[(wv * 64 + rb + r) * 8 + e] = lg[r][e];
    }
  }
  __syncthreads();

  // top-2 + sparse softmax + write + load-balance partials
  if (tid < BM) {
    float v[8];
#pragma unroll
    for (int e = 0; e < 8; ++e) {
      float s = b2[e];
#pragma unroll
      for (int w = 0; w < 8; ++w) s += eLog[(w * 64 + tid) * 8 + e];
      v[e] = s;
    }
    float m1 = v[0];
    int i1 = 0;
#pragma unroll
    for (int e = 1; e < 8; ++e)
      if (v[e] > m1) { m1 = v[e]; i1 = e; }   // strict >: lowest index wins ties
    float m2 = -3.0e38f;
    int i2 = -1;
#pragma unroll
    for (int e = 0; e < 8; ++e)
      if (e != i1 && v[e] > m2) { m2 = v[e]; i2 = e; }
    float dd = expf(m2 - m1);
    float inv = 1.0f / (1.0f + dd);
    float wA = inv, wB = dd * inv;
    float o[8];
#pragma unroll
    for (int e = 0; e < 8; ++e)
      o[e] = (e == i1) ? wA : ((e == i2) ? wB : 0.0f);
    float4* op = (float4*)&out[(row0 + tid) * 8];
    op[0] = (float4){o[0], o[1], o[2], o[3]};
    op[1] = (float4){o[4], o[5], o[6], o[7]};
    atomicAdd(&eFP[i1], 1.0f);
    atomicAdd(&eFP[i2], 1.0f);
    atomicAdd(&eFP[8 + i1], wA);
    atomicAdd(&eFP[8 + i2], wB);
  }
  __syncthreads();
  if (tid < 16) atomicAdd(&gacc[tid], eFP[tid]);
}

// ---- finalize load-balance loss --------------------------------------------
__global__ void lb_final(const float* __restrict__ gacc, float* __restrict__ out) {
  if (threadIdx.x == 0) {
    const float invB = 1.0f / 65536.0f;
    float s = 0.0f;
#pragma unroll
    for (int e = 0; e < 8; ++e) s += (gacc[e] * invB) * (gacc[8 + e] * invB);
    out[(size_t)B_ROWS * E_DIM] = 0.01f * 8.0f * s;
  }
}

// ---- launch ----------------------------------------------------------------
extern "C" void kernel_launch(void* const* d_in, const int* in_sizes, int n_in,
                              void* d_out, int out_size, void* d_ws, size_t ws_size,
                              hipStream_t stream) {
  (void)in_sizes; (void)n_in; (void)out_size; (void)ws_size;
  const float* x = (const float*)d_in[0];
  const float* W1 = (const float*)d_in[1];
  const float* b1 = (const float*)d_in[2];
  const float* lnw = (const float*)d_in[3];
  const float* lnb = (const float*)d_in[4];
  const float* W2 = (const float*)d_in[5];
  const float* b2 = (const float*)d_in[6];
  float* out = (float*)d_out;
  f16* wh = (f16*)d_ws;
  f16* wl = wh + IMG_TOTAL;
  float* gacc = (float*)((char*)d_ws + GACC_OFF);  // ws needs ~2.1 MB

  zero_acc<<<1, 64, 0, stream>>>(gacc);
  prep_split<<<(D_DIM * H_DIM / 8) / 256, 256, 0, stream>>>(W1, wh, wl);
  fused_main<<<B_ROWS / BM, THREADS, 0, stream>>>(x, wh, wl, b1, lnw, lnb, W2, b2,
                                                  out, gacc);
  lb_final<<<1, 64, 0, stream>>>(gacc, out);
}

// Round 6
// 249.716 us; speedup vs baseline: 1.4736x; 1.1040x over previous
//
#include <hip/hip_runtime.h>
#include <cstdint>
#include <cstddef>

// ---------------------------------------------------------------------------
// GatingNetwork r6: R5's rolling B-pipeline (raw lgkm-only barriers, loads in
// flight across barriers) at R2's occupancy (2 blocks/CU, 4 waves/SIMD).
// Register floor-plan: acc 64 AGPR + setB[2][4]=32 VGPR + xv 4 + temps -> <=64
// VGPR enforced by __launch_bounds__(512,4). Epilogue de-registered (W2 via
// padded LDS, per-r logit accumulation).
// Numerics (r1-r5 verified): A=64x hi/lo fp16, B=64w hi/lo fp16 (lo x2^8);
// 3-product Markidis MFMA 16x16x32; h at scale 2^12; fused LN/GELU/top2.
// ---------------------------------------------------------------------------

typedef _Float16 f16;
typedef _Float16 f16x4 __attribute__((ext_vector_type(4)));
typedef _Float16 f16x8 __attribute__((ext_vector_type(8)));
typedef float f32x4 __attribute__((ext_vector_type(4)));

#define B_ROWS 65536
#define D_DIM 1024
#define H_DIM 512
#define E_DIM 8
#define BM 64
#define BK 32
#define THREADS 512
#define NCHUNK 32
#define LDPX 40                          // slab row stride in halves (80 B)
#define SLABH 2560                       // 64 rows x 40 halves (one image)
#define BUFH 5120                        // hi + lo per buffer
#define IMG_CH (H_DIM * BK)              // 16384 halves per K-chunk B image
#define IMG_TOTAL (32 * IMG_CH)          // 1 MB per image
#define GACC_OFF ((size_t)2 * IMG_TOTAL * sizeof(f16))  // 2 MB

// ---- prep: split W1 into fp16 hi/lo images in MFMA B-fragment order --------
__global__ void prep_split(const float* __restrict__ W1,
                           f16* __restrict__ wh, f16* __restrict__ wl) {
  int id = blockIdx.x * 256 + threadIdx.x;   // 65536 threads
  int h = id & (H_DIM - 1);
  int kg = id >> 9;                          // 0..127
  int c = kg >> 2;
  int kk0 = (kg & 3) * 8;
  int k0 = kg * 8;
  f16x8 hv, lv;
#pragma unroll
  for (int j = 0; j < 8; ++j) {
    float v = W1[(size_t)(k0 + j) * H_DIM + h] * 64.0f;
    f16 hi = (f16)v;
    hv[j] = hi;
    lv[j] = (f16)((v - (float)hi) * 256.0f);  // residual pre-scaled 2^8
  }
  size_t o = (size_t)c * IMG_CH + (size_t)h * BK + kk0;
  *(f16x8*)&wh[o] = hv;
  *(f16x8*)&wl[o] = lv;
}

__global__ void zero_acc(float* __restrict__ acc) {
  if (threadIdx.x < 16) acc[threadIdx.x] = 0.0f;
}

// ---- main fused kernel -----------------------------------------------------
__global__ __launch_bounds__(THREADS, 4) void fused_main(
    const float* __restrict__ x,
    const f16* __restrict__ wh, const f16* __restrict__ wl,
    const float* __restrict__ b1, const float* __restrict__ lnw,
    const float* __restrict__ lnb, const float* __restrict__ W2,
    const float* __restrict__ b2, float* __restrict__ out,
    float* __restrict__ gacc) {
  // GEMM uses [0,20480) (2 x-slab buffers). Epilogue overlays [0,45632).
  __shared__ __align__(16) char pool[45632];
  f16* sx = (f16*)pool;

  const int tid = threadIdx.x;
  const int lane = tid & 63;
  const int wv = tid >> 6;        // 0..7 : wave owns cols wv*64..+63, all 64 rows
  const int l15 = lane & 15;
  const int l4 = lane >> 4;       // 0..3
  const int64_t row0 = (int64_t)blockIdx.x * BM;

  // staging: thread stages row tid>>3, 4 floats at k-offset (tid&7)*4
  const int srow = tid >> 3;
  const int sc4 = (tid & 7) * 4;
  const int swo = srow * LDPX + sc4;
  const float* xbase = x + (row0 + srow) * D_DIM + sc4;

  // B lane base (fragment-order image, r2-verified)
  const f16* whp = wh + (wv * 64 + l15) * BK + l4 * 8;

  f32x4 acc[4][4];
#pragma unroll
  for (int m = 0; m < 4; ++m)
#pragma unroll
    for (int n = 0; n < 4; ++n) acc[m][n] = (f32x4){0.f, 0.f, 0.f, 0.f};

  // two half-chunk B register sets: [set][0..1]=hi frags, [2..3]=lo frags
  f16x8 setB[2][4];

#define ISSUE(si, C, half)                                                    \
  do {                                                                        \
    const f16* p = whp + (size_t)((C) & 31) * IMG_CH + (half) * 1024;         \
    setB[si][0] = *(const f16x8*)(p);                                         \
    setB[si][1] = *(const f16x8*)(p + 512);                                   \
    setB[si][2] = *(const f16x8*)(p + IMG_TOTAL);                             \
    setB[si][3] = *(const f16x8*)(p + IMG_TOTAL + 512);                       \
  } while (0)

#define CHUNK_HALF(si, nh, bufv)                                              \
  do {                                                                        \
    __builtin_amdgcn_s_setprio(1);                                            \
    _Pragma("unroll") for (int m = 0; m < 4; ++m) {                           \
      const int ao = (bufv)*BUFH + (m * 16 + l15) * LDPX + l4 * 8;            \
      f16x8 ah = *(const f16x8*)&sx[ao];                                      \
      f16x8 al = *(const f16x8*)&sx[ao + SLABH];                              \
      f16x8 ahs;                                                              \
      _Pragma("unroll") for (int q = 0; q < 8; ++q) ahs[q] =                  \
          ah[q] * (f16)0.00390625f;                                           \
      acc[m][(nh)*2 + 0] = __builtin_amdgcn_mfma_f32_16x16x32_f16(            \
          ah, setB[si][0], acc[m][(nh)*2 + 0], 0, 0, 0);                      \
      acc[m][(nh)*2 + 0] = __builtin_amdgcn_mfma_f32_16x16x32_f16(            \
          al, setB[si][0], acc[m][(nh)*2 + 0], 0, 0, 0);                      \
      acc[m][(nh)*2 + 0] = __builtin_amdgcn_mfma_f32_16x16x32_f16(            \
          ahs, setB[si][2], acc[m][(nh)*2 + 0], 0, 0, 0);                     \
      acc[m][(nh)*2 + 1] = __builtin_amdgcn_mfma_f32_16x16x32_f16(            \
          ah, setB[si][1], acc[m][(nh)*2 + 1], 0, 0, 0);                      \
      acc[m][(nh)*2 + 1] = __builtin_amdgcn_mfma_f32_16x16x32_f16(            \
          al, setB[si][1], acc[m][(nh)*2 + 1], 0, 0, 0);                      \
      acc[m][(nh)*2 + 1] = __builtin_amdgcn_mfma_f32_16x16x32_f16(            \
          ahs, setB[si][3], acc[m][(nh)*2 + 1], 0, 0, 0);                     \
    }                                                                         \
    __builtin_amdgcn_s_setprio(0);                                            \
  } while (0)

#define WRITE_SLAB(bufv)                                                      \
  do {                                                                        \
    float vv[4] = {xv.x, xv.y, xv.z, xv.w};                                   \
    f16x4 hv, lv;                                                             \
    _Pragma("unroll") for (int q = 0; q < 4; ++q) {                           \
      float t = vv[q] * 64.0f;                                                \
      f16 hh = (f16)t;                                                        \
      hv[q] = hh;                                                             \
      lv[q] = (f16)(t - (float)hh);                                           \
    }                                                                         \
    *(f16x4*)&sx[(bufv)*BUFH + swo] = hv;                                     \
    *(f16x4*)&sx[(bufv)*BUFH + SLABH + swo] = lv;                             \
  } while (0)

  // raw barrier: drain only LDS ops, keep global loads in flight (T4)
#define SLAB_BARRIER()                                                        \
  do {                                                                        \
    asm volatile("s_waitcnt lgkmcnt(0)" ::: "memory");                        \
    __builtin_amdgcn_s_barrier();                                             \
    __builtin_amdgcn_sched_barrier(0);                                        \
  } while (0)

  // ---- prologue: slab chunk0, B sets for chunk0 halves, xv <- chunk1 ------
  float4 xv = *(const float4*)(xbase);
  WRITE_SLAB(0);
  ISSUE(0, 0, 0);
  ISSUE(1, 0, 1);
  xv = *(const float4*)(xbase + 32);
  SLAB_BARRIER();

  for (int c = 0; c < NCHUNK; ++c) {
    const int buf = c & 1;
    CHUNK_HALF(0, 0, buf);        // chunk c, frags n0/n1 (set issued 1 chunk ago)
    ISSUE(0, c + 1, 0);           // refill set0 for chunk c+1
    CHUNK_HALF(1, 1, buf);        // chunk c, frags n2/n3
    ISSUE(1, c + 1, 1);           // refill set1 for chunk c+1
    WRITE_SLAB(buf ^ 1);          // slab chunk c+1 (xv loaded last iteration)
    xv = *(const float4*)(xbase + ((c + 2) & 31) * 32);  // x for chunk c+2
    SLAB_BARRIER();
  }
#undef ISSUE
#undef CHUNK_HALF
#undef WRITE_SLAB
#undef SLAB_BARRIER
  __syncthreads();  // full drain before overlaying epilogue LDS

  // ---------------- epilogue (h at scale 2^12 in acc) -----------------------
  float* eW2T = (float*)pool;              // [512][12] padded = 24576 B
  float* eStat = (float*)(pool + 24576);   // [8][64][2] = 4096 B
  float* eLog = (float*)(pool + 28672);    // [8][64][8] = 16384 B
  float* eMu = (float*)(pool + 45056);     // [64]
  float* eRs = (float*)(pool + 45312);     // [64]
  float* eFP = (float*)(pool + 45568);     // [16]

  // stage W2 (each thread owns one column h = tid)
  {
    float4 wa = *(const float4*)&W2[tid * 8];
    float4 wb = *(const float4*)&W2[tid * 8 + 4];
    *(float4*)&eW2T[tid * 12] = wa;
    *(float4*)&eW2T[tid * 12 + 4] = wb;
  }
  if (tid < 16) eFP[tid] = 0.0f;

  // h += b1 (scaled); per-column params from L2 (tiny + hot)
  float bb[4], lw[4], lb[4];
#pragma unroll
  for (int n = 0; n < 4; ++n) {
    int col = wv * 64 + n * 16 + l15;
    bb[n] = b1[col] * 4096.0f;
    lw[n] = lnw[col];
    lb[n] = lnb[col];
#pragma unroll
    for (int m = 0; m < 4; ++m)
#pragma unroll
      for (int r = 0; r < 4; ++r) acc[m][n][r] += bb[n];
  }

  // row stats: partial over this wave's 64 cols, deterministic combine
#pragma unroll
  for (int m = 0; m < 4; ++m) {
    float s1[4] = {0, 0, 0, 0};
    float s2[4] = {0, 0, 0, 0};
#pragma unroll
    for (int n = 0; n < 4; ++n)
#pragma unroll
      for (int r = 0; r < 4; ++r) {
        float vv = acc[m][n][r];
        s1[r] += vv;
        s2[r] = fmaf(vv, vv, s2[r]);
      }
#pragma unroll
    for (int d = 1; d < 16; d <<= 1)
#pragma unroll
      for (int r = 0; r < 4; ++r) {
        s1[r] += __shfl_xor(s1[r], d);
        s2[r] += __shfl_xor(s2[r], d);
      }
    if (l15 == 0) {
      int rb = m * 16 + l4 * 4;
#pragma unroll
      for (int r = 0; r < 4; ++r) {
        eStat[(wv * 64 + rb + r) * 2 + 0] = s1[r];
        eStat[(wv * 64 + rb + r) * 2 + 1] = s2[r];
      }
    }
  }
  __syncthreads();
  if (tid < BM) {
    float s1 = 0.0f, s2 = 0.0f;
#pragma unroll
    for (int w = 0; w < 8; ++w) {
      s1 += eStat[(w * 64 + tid) * 2 + 0];
      s2 += eStat[(w * 64 + tid) * 2 + 1];
    }
    float mu = s1 * (1.0f / 512.0f);
    float var = s2 * (1.0f / 512.0f) - mu * mu;
    eMu[tid] = mu;
    eRs[tid] = 1.0f / sqrtf(var + (1e-5f * 4096.0f * 4096.0f));
  }
  __syncthreads();

  // LN + exact-erf GELU + per-wave partial logits (per-r accumulation: 8 regs)
#pragma unroll
  for (int m = 0; m < 4; ++m) {
    int rb = m * 16 + l4 * 4;
#pragma unroll
    for (int r = 0; r < 4; ++r) {
      float mu_r = eMu[rb + r];
      float rs_r = eRs[rb + r];
      float lg[8];
#pragma unroll
      for (int e = 0; e < 8; ++e) lg[e] = 0.0f;
#pragma unroll
      for (int n = 0; n < 4; ++n) {
        int col = wv * 64 + n * 16 + l15;
        float hn = (acc[m][n][r] - mu_r) * rs_r;
        float y = fmaf(hn, lw[n], lb[n]);
        float g = 0.5f * y * (1.0f + erff(y * 0.70710678118654752440f));
        float4 w0 = *(const float4*)&eW2T[col * 12];
        float4 w1 = *(const float4*)&eW2T[col * 12 + 4];
        lg[0] = fmaf(g, w0.x, lg[0]);
        lg[1] = fmaf(g, w0.y, lg[1]);
        lg[2] = fmaf(g, w0.z, lg[2]);
        lg[3] = fmaf(g, w0.w, lg[3]);
        lg[4] = fmaf(g, w1.x, lg[4]);
        lg[5] = fmaf(g, w1.y, lg[5]);
        lg[6] = fmaf(g, w1.z, lg[6]);
        lg[7] = fmaf(g, w1.w, lg[7]);
      }
#pragma unroll
      for (int d = 1; d < 16; d <<= 1)
#pragma unroll
        for (int e = 0; e < 8; ++e) lg[e] += __shfl_xor(lg[e], d);
      if (l15 == 0) {
#pragma unroll
        for (int e = 0; e < 8; ++e) eLog[(wv * 64 + rb + r) * 8 + e] = lg[e];
      }
    }
  }
  __syncthreads();

  // top-2 + sparse softmax + write + load-balance partials
  if (tid < BM) {
    float v[8];
#pragma unroll
    for (int e = 0; e < 8; ++e) {
      float s = b2[e];
#pragma unroll
      for (int w = 0; w < 8; ++w) s += eLog[(w * 64 + tid) * 8 + e];
      v[e] = s;
    }
    float m1 = v[0];
    int i1 = 0;
#pragma unroll
    for (int e = 1; e < 8; ++e)
      if (v[e] > m1) { m1 = v[e]; i1 = e; }   // strict >: lowest index wins ties
    float m2 = -3.0e38f;
    int i2 = -1;
#pragma unroll
    for (int e = 0; e < 8; ++e)
      if (e != i1 && v[e] > m2) { m2 = v[e]; i2 = e; }
    float dd = expf(m2 - m1);
    float inv = 1.0f / (1.0f + dd);
    float wA = inv, wB = dd * inv;
    float o[8];
#pragma unroll
    for (int e = 0; e < 8; ++e)
      o[e] = (e == i1) ? wA : ((e == i2) ? wB : 0.0f);
    float4* op = (float4*)&out[(row0 + tid) * 8];
    op[0] = (float4){o[0], o[1], o[2], o[3]};
    op[1] = (float4){o[4], o[5], o[6], o[7]};
    atomicAdd(&eFP[i1], 1.0f);
    atomicAdd(&eFP[i2], 1.0f);
    atomicAdd(&eFP[8 + i1], wA);
    atomicAdd(&eFP[8 + i2], wB);
  }
  __syncthreads();
  if (tid < 16) atomicAdd(&gacc[tid], eFP[tid]);
}

// ---- finalize load-balance loss --------------------------------------------
__global__ void lb_final(const float* __restrict__ gacc, float* __restrict__ out) {
  if (threadIdx.x == 0) {
    const float invB = 1.0f / 65536.0f;
    float s = 0.0f;
#pragma unroll
    for (int e = 0; e < 8; ++e) s += (gacc[e] * invB) * (gacc[8 + e] * invB);
    out[(size_t)B_ROWS * E_DIM] = 0.01f * 8.0f * s;
  }
}

// ---- launch ----------------------------------------------------------------
extern "C" void kernel_launch(void* const* d_in, const int* in_sizes, int n_in,
                              void* d_out, int out_size, void* d_ws, size_t ws_size,
                              hipStream_t stream) {
  (void)in_sizes; (void)n_in; (void)out_size; (void)ws_size;
  const float* x = (const float*)d_in[0];
  const float* W1 = (const float*)d_in[1];
  const float* b1 = (const float*)d_in[2];
  const float* lnw = (const float*)d_in[3];
  const float* lnb = (const float*)d_in[4];
  const float* W2 = (const float*)d_in[5];
  const float* b2 = (const float*)d_in[6];
  float* out = (float*)d_out;
  f16* wh = (f16*)d_ws;
  f16* wl = wh + IMG_TOTAL;
  float* gacc = (float*)((char*)d_ws + GACC_OFF);  // ws needs ~2.1 MB

  zero_acc<<<1, 64, 0, stream>>>(gacc);
  prep_split<<<(D_DIM * H_DIM / 8) / 256, 256, 0, stream>>>(W1, wh, wl);
  fused_main<<<B_ROWS / BM, THREADS, 0, stream>>>(x, wh, wl, b1, lnw, lnb, W2, b2,
                                                  out, gacc);
  lb_final<<<1, 64, 0, stream>>>(gacc, out);
}